// Round 1
// baseline (278.681 us; speedup 1.0000x reference)
//
#include <hip/hip_runtime.h>
#include <math.h>

#define B_DIM 256
#define T_DIM 8192
#define BLOCK 256
#define CHUNKS_PER_B (T_DIM / BLOCK)   // 32

// ws layout (doubles):
// 0 robot_sse, 1 nll_sum, 2 coher_sum, 3 coher_cnt, 4 pen2_sum, 5 velsq_sum, 6 accsq_sum

__global__ __launch_bounds__(BLOCK) void combined_loss_main(
    const float* __restrict__ pred_robot,
    const float* __restrict__ pred_phase,
    const float* __restrict__ gt_robot,
    const int*   __restrict__ gt_phase,
    double* __restrict__ ws)
{
    // transposed robot tile: row-read s[k][tid+c] is unit-stride across lanes -> conflict-free
    __shared__ float s_robot[12][BLOCK + 2];
    __shared__ float s_phase[3][BLOCK + 1];
    __shared__ float s_red[4][8];

    const int tid   = threadIdx.x;
    const int b     = blockIdx.x >> 5;       // / CHUNKS_PER_B
    const int chunk = blockIdx.x & 31;
    const int t0    = chunk << 8;            // * BLOCK
    const int t     = t0 + tid;

    const size_t row = (size_t)b * T_DIM + t;
    const float* pr = pred_robot + row * 12;
    const float* gr = gt_robot   + row * 12;
    const float* pp = pred_phase + row * 3;

    float r[12], g[12];
    {
        float4 v0 = *(const float4*)(pr);
        float4 v1 = *(const float4*)(pr + 4);
        float4 v2 = *(const float4*)(pr + 8);
        r[0]=v0.x; r[1]=v0.y; r[2]=v0.z; r[3]=v0.w;
        r[4]=v1.x; r[5]=v1.y; r[6]=v1.z; r[7]=v1.w;
        r[8]=v2.x; r[9]=v2.y; r[10]=v2.z; r[11]=v2.w;
        float4 w0 = *(const float4*)(gr);
        float4 w1 = *(const float4*)(gr + 4);
        float4 w2 = *(const float4*)(gr + 8);
        g[0]=w0.x; g[1]=w0.y; g[2]=w0.z; g[3]=w0.w;
        g[4]=w1.x; g[5]=w1.y; g[6]=w1.z; g[7]=w1.w;
        g[8]=w2.x; g[9]=w2.y; g[10]=w2.z; g[11]=w2.w;
    }

    // robot MSE partial (pointwise, registers only)
    float sse = 0.0f;
    #pragma unroll
    for (int k = 0; k < 12; ++k) { float d = r[k] - g[k]; sse += d * d; }

    // stage own robot row (transposed) + phase row into LDS
    #pragma unroll
    for (int k = 0; k < 12; ++k) s_robot[k][tid] = r[k];

    const float l0 = pp[0], l1 = pp[1], l2 = pp[2];
    s_phase[0][tid] = l0; s_phase[1][tid] = l1; s_phase[2][tid] = l2;

    // halo rows t0+256, t0+257 (robot) and t0+256 (phase)
    if (tid < 2) {
        const int th = t0 + BLOCK + tid;
        if (th < T_DIM) {
            const float* ph = pred_robot + ((size_t)b * T_DIM + th) * 12;
            #pragma unroll
            for (int k = 0; k < 12; ++k) s_robot[k][BLOCK + tid] = ph[k];
            if (tid == 0) {
                const float* pq = pred_phase + ((size_t)b * T_DIM + th) * 3;
                s_phase[0][BLOCK] = pq[0];
                s_phase[1][BLOCK] = pq[1];
                s_phase[2][BLOCK] = pq[2];
            }
        }
    }

    // phase NLL (stable logsumexp over 3)
    const int gidx = gt_phase[row];
    float m = fmaxf(l0, fmaxf(l1, l2));
    float lse = m + logf(expf(l0 - m) + expf(l1 - m) + expf(l2 - m));
    float sel = (gidx == 0) ? l0 : ((gidx == 1) ? l1 : l2);
    float nll = lse - sel;

    // own argmax (first-index tie-break, matches jnp.argmax)
    int p = 0; float pm = l0;
    if (l1 > pm) { pm = l1; p = 1; }
    if (l2 > pm) { pm = l2; p = 2; }

    __syncthreads();

    float csum = 0.0f, ccnt = 0.0f, pen2 = 0.0f, velsq = 0.0f, accsq = 0.0f;

    if (t < T_DIM - 1) {
        float r1[12];
        #pragma unroll
        for (int k = 0; k < 12; ++k) r1[k] = s_robot[k][tid + 1];

        float vel[12];
        #pragma unroll
        for (int k = 0; k < 12; ++k) { vel[k] = r1[k] - r[k]; velsq += vel[k] * vel[k]; }

        #pragma unroll
        for (int j = 0; j < 4; ++j) {
            float sx = vel[3*j], sy = vel[3*j+1], sz = vel[3*j+2];
            float sp = sqrtf(sx*sx + sy*sy + sz*sz);
            float d = sp - 10.0f;
            if (d > 0.0f) pen2 += d * d;
        }

        // coherence: (argmax_t, argmax_{t+1}); sel is max logit at t+1
        float n0 = s_phase[0][tid + 1], n1 = s_phase[1][tid + 1], n2 = s_phase[2][tid + 1];
        int p1 = 0; float m1 = n0;
        if (n1 > m1) { m1 = n1; p1 = 1; }
        if (n2 > m1) { m1 = n2; p1 = 2; }
        // illegal pairs: (0,2),(1,0),(2,0),(2,1) -> bitmask over p1 per p: {0b100, 0b001, 0b011}
        int mask = (p == 0) ? 4 : ((p == 1) ? 1 : 3);
        if ((mask >> p1) & 1) { csum += m1 * m1; ccnt += 1.0f; }

        if (t < T_DIM - 2) {
            #pragma unroll
            for (int k = 0; k < 12; ++k) {
                float a = s_robot[k][tid + 2] - 2.0f * r1[k] + r[k];
                accsq += a * a;
            }
        }
    }

    // block reduction: wave64 shuffle -> LDS cross-wave -> double atomics
    float vals[7] = { sse, nll, csum, ccnt, pen2, velsq, accsq };
    #pragma unroll
    for (int off = 32; off > 0; off >>= 1) {
        #pragma unroll
        for (int q = 0; q < 7; ++q)
            vals[q] += __shfl_down(vals[q], off, 64);
    }
    const int wave = tid >> 6, lane = tid & 63;
    if (lane == 0) {
        #pragma unroll
        for (int q = 0; q < 7; ++q) s_red[wave][q] = vals[q];
    }
    __syncthreads();
    if (tid < 7) {
        double acc = (double)s_red[0][tid] + (double)s_red[1][tid]
                   + (double)s_red[2][tid] + (double)s_red[3][tid];
        atomicAdd(&ws[tid], acc);
    }
}

__global__ void combined_loss_final(const double* __restrict__ ws, float* __restrict__ out)
{
    const double robot = ws[0] / (double)((size_t)B_DIM * T_DIM * 12);
    const double phase = ws[1] / (double)((size_t)B_DIM * T_DIM);
    const double coher = (ws[3] > 0.0) ? (ws[2] / fmax(ws[3], 1.0)) : 0.0;
    const double speed = 5.0  * (ws[4] / (double)((size_t)B_DIM * (T_DIM - 1) * 4));
    const double vel   = 0.05 * (ws[5] / (double)((size_t)B_DIM * (T_DIM - 1) * 12));
    const double acc   = 0.01 * (ws[6] / (double)((size_t)B_DIM * (T_DIM - 2) * 12));
    out[0] = (float)(robot + phase + 10.0 * coher + speed + vel + acc);
}

extern "C" void kernel_launch(void* const* d_in, const int* in_sizes, int n_in,
                              void* d_out, int out_size, void* d_ws, size_t ws_size,
                              hipStream_t stream)
{
    const float* pred_robot = (const float*)d_in[0];
    const float* pred_phase = (const float*)d_in[1];
    const float* gt_robot   = (const float*)d_in[2];
    const int*   gt_phase   = (const int*)d_in[3];
    double* ws  = (double*)d_ws;
    float*  out = (float*)d_out;

    hipMemsetAsync(d_ws, 0, 7 * sizeof(double), stream);

    const dim3 grid(B_DIM * CHUNKS_PER_B);  // 8192 blocks
    combined_loss_main<<<grid, BLOCK, 0, stream>>>(pred_robot, pred_phase, gt_robot, gt_phase, ws);
    combined_loss_final<<<1, 1, 0, stream>>>(ws, out);
}

// Round 2
// 240.142 us; speedup vs baseline: 1.1605x; 1.1605x over previous
//
#include <hip/hip_runtime.h>
#include <math.h>

#define B_DIM 256
#define T_DIM 8192
#define BLOCK 256
#define CHUNKS_PER_B (T_DIM / BLOCK)   // 32
#define NSLOT 256                      // atomic spreading slots (stride 8 doubles = 16 KB ws)

// ws layout: NSLOT slots x 8 doubles; within a slot:
// 0 robot_sse, 1 nll_sum, 2 coher_sum, 3 coher_cnt, 4 pen2_sum, 5 velsq_sum, 6 accsq_sum

__global__ __launch_bounds__(BLOCK) void combined_loss_main(
    const float4* __restrict__ pred4,
    const float*  __restrict__ pred_phase,
    const float4* __restrict__ gt4,
    const int*    __restrict__ gt_phase,
    double* __restrict__ ws)
{
    // flat-staged pred tile: 256 rows * 3 float4 + 2 halo rows (6 float4)
    __shared__ float4 sp[774];
    __shared__ float  s_ph[776];       // 258 rows * 3 floats (774 used)
    __shared__ float  s_red[4][8];

    const int tid   = threadIdx.x;
    const int b     = blockIdx.x >> 5;       // / CHUNKS_PER_B
    const int chunk = blockIdx.x & 31;
    const int t0    = chunk << 8;
    const int t     = t0 + tid;

    const size_t row0  = (size_t)b * T_DIM + t0;
    const size_t base4 = row0 * 3;                    // float4 index of robot tile start
    const float4* ph4  = (const float4*)pred_phase + ((row0 * 3) >> 2); // 16B-aligned (row0*3 % 256 == 0)
    const bool halo = (t0 + BLOCK) < T_DIM;

    // ---- all global loads issued up front, fully lane-coalesced ----
    float4 p0 = pred4[base4 + tid];
    float4 p1 = pred4[base4 + tid + 256];
    float4 p2 = pred4[base4 + tid + 512];
    float4 g0 = gt4[base4 + tid];
    float4 g1 = gt4[base4 + tid + 256];
    float4 g2 = gt4[base4 + tid + 512];
    float4 ph = make_float4(0.f, 0.f, 0.f, 0.f);
    if (tid < 192) ph = ph4[tid];                     // 768 floats = 256 phase rows
    const int gidx = gt_phase[row0 + tid];
    if (halo && tid >= 248 && tid < 254)              // 6 halo float4s (rows t0+256, t0+257)
        sp[768 + (tid - 248)] = pred4[base4 + 768 + (tid - 248)];
    if (halo && tid >= 192 && tid < 198)              // 6 halo phase floats
        s_ph[768 + (tid - 192)] = pred_phase[row0 * 3 + 768 + (tid - 192)];

    // ---- robot MSE in the flat domain (order-independent) ----
    float sse = 0.0f;
    {
        float d;
        d = p0.x - g0.x; sse += d*d;  d = p0.y - g0.y; sse += d*d;
        d = p0.z - g0.z; sse += d*d;  d = p0.w - g0.w; sse += d*d;
        d = p1.x - g1.x; sse += d*d;  d = p1.y - g1.y; sse += d*d;
        d = p1.z - g1.z; sse += d*d;  d = p1.w - g1.w; sse += d*d;
        d = p2.x - g2.x; sse += d*d;  d = p2.y - g2.y; sse += d*d;
        d = p2.z - g2.z; sse += d*d;  d = p2.w - g2.w; sse += d*d;
    }

    // ---- stage pred + phase tiles flat into LDS ----
    sp[tid]       = p0;
    sp[tid + 256] = p1;
    sp[tid + 512] = p2;
    if (tid < 192) *((float4*)&s_ph[4 * tid]) = ph;
    __syncthreads();

    // ---- per-row stencil work (LDS only) ----
    const float l0 = s_ph[3*tid], l1 = s_ph[3*tid + 1], l2 = s_ph[3*tid + 2];
    float m = fmaxf(l0, fmaxf(l1, l2));
    float lse = m + logf(expf(l0 - m) + expf(l1 - m) + expf(l2 - m));
    float sel = (gidx == 0) ? l0 : ((gidx == 1) ? l1 : l2);
    float nll = lse - sel;

    int p = 0; float pm = l0;
    if (l1 > pm) { pm = l1; p = 1; }
    if (l2 > pm) { pm = l2; p = 2; }

    float csum = 0.0f, ccnt = 0.0f, pen2 = 0.0f, velsq = 0.0f, accsq = 0.0f;

    float4 a0 = sp[tid*3], a1 = sp[tid*3 + 1], a2 = sp[tid*3 + 2];
    float rA[12] = { a0.x,a0.y,a0.z,a0.w, a1.x,a1.y,a1.z,a1.w, a2.x,a2.y,a2.z,a2.w };

    if (t < T_DIM - 1) {
        float4 b0 = sp[tid*3 + 3], b1 = sp[tid*3 + 4], b2 = sp[tid*3 + 5];
        float rB[12] = { b0.x,b0.y,b0.z,b0.w, b1.x,b1.y,b1.z,b1.w, b2.x,b2.y,b2.z,b2.w };

        float vel[12];
        #pragma unroll
        for (int k = 0; k < 12; ++k) { vel[k] = rB[k] - rA[k]; velsq += vel[k]*vel[k]; }

        #pragma unroll
        for (int j = 0; j < 4; ++j) {
            float sx = vel[3*j], sy = vel[3*j+1], sz = vel[3*j+2];
            float sp2 = sqrtf(sx*sx + sy*sy + sz*sz);
            float d = sp2 - 10.0f;
            if (d > 0.0f) pen2 += d*d;
        }

        // coherence: argmax at t vs t+1; sel is max logit at t+1
        float n0 = s_ph[3*tid + 3], n1 = s_ph[3*tid + 4], n2 = s_ph[3*tid + 5];
        int p1i = 0; float m1 = n0;
        if (n1 > m1) { m1 = n1; p1i = 1; }
        if (n2 > m1) { m1 = n2; p1i = 2; }
        int mask = (p == 0) ? 4 : ((p == 1) ? 1 : 3);  // illegal: (0,2),(1,0),(2,0),(2,1)
        if ((mask >> p1i) & 1) { csum += m1*m1; ccnt += 1.0f; }

        if (t < T_DIM - 2) {
            float4 c0 = sp[tid*3 + 6], c1 = sp[tid*3 + 7], c2 = sp[tid*3 + 8];
            float rC[12] = { c0.x,c0.y,c0.z,c0.w, c1.x,c1.y,c1.z,c1.w, c2.x,c2.y,c2.z,c2.w };
            #pragma unroll
            for (int k = 0; k < 12; ++k) {
                float a = rC[k] - 2.0f*rB[k] + rA[k];
                accsq += a*a;
            }
        }
    }

    // ---- block reduction: wave64 shuffle -> LDS -> slotted fp64 atomics ----
    float vals[7] = { sse, nll, csum, ccnt, pen2, velsq, accsq };
    #pragma unroll
    for (int off = 32; off > 0; off >>= 1) {
        #pragma unroll
        for (int q = 0; q < 7; ++q)
            vals[q] += __shfl_down(vals[q], off, 64);
    }
    const int wave = tid >> 6, lane = tid & 63;
    if (lane == 0) {
        #pragma unroll
        for (int q = 0; q < 7; ++q) s_red[wave][q] = vals[q];
    }
    __syncthreads();
    if (tid < 7) {
        double acc = (double)s_red[0][tid] + (double)s_red[1][tid]
                   + (double)s_red[2][tid] + (double)s_red[3][tid];
        atomicAdd(&ws[(size_t)(blockIdx.x & (NSLOT - 1)) * 8 + tid], acc);
    }
}

__global__ __launch_bounds__(256) void combined_loss_final(
    const double* __restrict__ ws, float* __restrict__ out)
{
    __shared__ double sred[4][7];
    const int tid = threadIdx.x;
    double v[7];
    #pragma unroll
    for (int q = 0; q < 7; ++q) v[q] = ws[(size_t)tid * 8 + q];  // one slot per thread
    #pragma unroll
    for (int off = 32; off > 0; off >>= 1) {
        #pragma unroll
        for (int q = 0; q < 7; ++q)
            v[q] += __shfl_down(v[q], off, 64);
    }
    const int wave = tid >> 6, lane = tid & 63;
    if (lane == 0) {
        #pragma unroll
        for (int q = 0; q < 7; ++q) sred[wave][q] = v[q];
    }
    __syncthreads();
    if (tid == 0) {
        double s[7];
        #pragma unroll
        for (int q = 0; q < 7; ++q)
            s[q] = sred[0][q] + sred[1][q] + sred[2][q] + sred[3][q];
        const double robot = s[0] / (double)((size_t)B_DIM * T_DIM * 12);
        const double phase = s[1] / (double)((size_t)B_DIM * T_DIM);
        const double coher = (s[3] > 0.0) ? (s[2] / fmax(s[3], 1.0)) : 0.0;
        const double speed = 5.0  * (s[4] / (double)((size_t)B_DIM * (T_DIM - 1) * 4));
        const double vel   = 0.05 * (s[5] / (double)((size_t)B_DIM * (T_DIM - 1) * 12));
        const double acc   = 0.01 * (s[6] / (double)((size_t)B_DIM * (T_DIM - 2) * 12));
        out[0] = (float)(robot + phase + 10.0 * coher + speed + vel + acc);
    }
}

extern "C" void kernel_launch(void* const* d_in, const int* in_sizes, int n_in,
                              void* d_out, int out_size, void* d_ws, size_t ws_size,
                              hipStream_t stream)
{
    const float4* pred4      = (const float4*)d_in[0];
    const float*  pred_phase = (const float*)d_in[1];
    const float4* gt4        = (const float4*)d_in[2];
    const int*    gt_phase   = (const int*)d_in[3];
    double* ws  = (double*)d_ws;
    float*  out = (float*)d_out;

    hipMemsetAsync(d_ws, 0, (size_t)NSLOT * 8 * sizeof(double), stream);

    const dim3 grid(B_DIM * CHUNKS_PER_B);  // 8192 blocks
    combined_loss_main<<<grid, BLOCK, 0, stream>>>(pred4, pred_phase, gt4, gt_phase, ws);
    combined_loss_final<<<1, 256, 0, stream>>>(ws, out);
}

// Round 4
// 237.726 us; speedup vs baseline: 1.1723x; 1.0102x over previous
//
#include <hip/hip_runtime.h>
#include <math.h>

#define B_DIM 256
#define T_DIM 8192
#define BLOCK 256
#define NSLOT 256
#define GRID_BLOCKS 8192   // one row per thread: 8192*256 = 2,097,152 rows

// ws layout: NSLOT slots x 8 doubles:
// 0 robot_sse, 1 nll_sum, 2 coher_sum, 3 coher_cnt, 4 pen2_sum, 5 velsq_sum, 6 accsq_sum

__global__ __launch_bounds__(BLOCK) void combined_loss_main(
    const float4* __restrict__ pred4,
    const float*  __restrict__ pred_phase,
    const float4* __restrict__ gt4,
    const int*    __restrict__ gt_phase,
    double* __restrict__ ws)
{
    __shared__ float s_red[4][8];

    const int tid = threadIdx.x;
    const int r   = (int)blockIdx.x * BLOCK + tid;    // flat row id in [0, B*T)
    const int t   = r & (T_DIM - 1);
    const bool v1 = (t < T_DIM - 1);
    const bool v2 = (t < T_DIM - 2);

    // ---- per-thread private loads (neighbor rows are L1-hot) ----
    const float4* pr = pred4 + (size_t)r * 3;
    const float4* gr = gt4   + (size_t)r * 3;
    const float*  pp = pred_phase + (size_t)r * 3;

    const int o1 = v1 ? 3 : 0;   // clamped offsets: always in-bounds
    const int o2 = v2 ? 6 : 0;

    float4 a0 = pr[0],      a1 = pr[1],      a2 = pr[2];       // row t
    float4 b0 = pr[o1],     b1 = pr[o1 + 1], b2 = pr[o1 + 2];  // row t+1
    float4 c0 = pr[o2],     c1 = pr[o2 + 1], c2 = pr[o2 + 2];  // row t+2
    float4 q0 = gr[0],      q1 = gr[1],      q2 = gr[2];

    const float l0 = pp[0],  l1 = pp[1],  l2 = pp[2];          // phase row t
    const float n0 = pp[o1], n1 = pp[o1 + 1], n2 = pp[o1 + 2]; // phase row t+1
    const int gidx = gt_phase[r];

    // ---- robot MSE ----
    float sse = 0.0f;
    {
        float d;
        d = a0.x - q0.x; sse += d*d;  d = a0.y - q0.y; sse += d*d;
        d = a0.z - q0.z; sse += d*d;  d = a0.w - q0.w; sse += d*d;
        d = a1.x - q1.x; sse += d*d;  d = a1.y - q1.y; sse += d*d;
        d = a1.z - q1.z; sse += d*d;  d = a1.w - q1.w; sse += d*d;
        d = a2.x - q2.x; sse += d*d;  d = a2.y - q2.y; sse += d*d;
        d = a2.z - q2.z; sse += d*d;  d = a2.w - q2.w; sse += d*d;
    }

    // ---- phase NLL (stable logsumexp over 3) ----
    float m = fmaxf(l0, fmaxf(l1, l2));
    float lse = m + logf(expf(l0 - m) + expf(l1 - m) + expf(l2 - m));
    float sel = (gidx == 0) ? l0 : ((gidx == 1) ? l1 : l2);
    float nll = lse - sel;

    // ---- coherence (argmax at t vs t+1, both private) ----
    float csum = 0.0f, ccnt = 0.0f;
    if (v1) {
        int p = 0; float pm = l0;
        if (l1 > pm) { pm = l1; p = 1; }
        if (l2 > pm) { pm = l2; p = 2; }
        int p1 = 0; float m1 = n0;
        if (n1 > m1) { m1 = n1; p1 = 1; }
        if (n2 > m1) { m1 = n2; p1 = 2; }
        int mask = (p == 0) ? 4 : ((p == 1) ? 1 : 3);  // illegal: (0,2),(1,0),(2,0),(2,1)
        if ((mask >> p1) & 1) { csum = m1 * m1; ccnt = 1.0f; }
    }

    // ---- stencil terms (all register-private) ----
    float pen2 = 0.0f, velsq = 0.0f, accsq = 0.0f;
    {
        float rA[12] = { a0.x,a0.y,a0.z,a0.w, a1.x,a1.y,a1.z,a1.w, a2.x,a2.y,a2.z,a2.w };
        float rB[12] = { b0.x,b0.y,b0.z,b0.w, b1.x,b1.y,b1.z,b1.w, b2.x,b2.y,b2.z,b2.w };
        float rC[12] = { c0.x,c0.y,c0.z,c0.w, c1.x,c1.y,c1.z,c1.w, c2.x,c2.y,c2.z,c2.w };

        if (v1) {
            float vel[12];
            #pragma unroll
            for (int k = 0; k < 12; ++k) { vel[k] = rB[k] - rA[k]; velsq += vel[k]*vel[k]; }

            #pragma unroll
            for (int j = 0; j < 4; ++j) {
                float sx = vel[3*j], sy = vel[3*j+1], sz = vel[3*j+2];
                float sp = sqrtf(sx*sx + sy*sy + sz*sz);
                float d = sp - 10.0f;
                if (d > 0.0f) pen2 += d*d;
            }

            if (v2) {
                #pragma unroll
                for (int k = 0; k < 12; ++k) {
                    float a = rC[k] - 2.0f*rB[k] + rA[k];
                    accsq += a*a;
                }
            }
        }
    }

    // ---- wave shuffle reduce -> one barrier -> slotted fp64 atomics ----
    float vals[7] = { sse, nll, csum, ccnt, pen2, velsq, accsq };
    #pragma unroll
    for (int off = 32; off > 0; off >>= 1) {
        #pragma unroll
        for (int q = 0; q < 7; ++q)
            vals[q] += __shfl_down(vals[q], off, 64);
    }
    const int wave = tid >> 6, lane = tid & 63;
    if (lane == 0) {
        #pragma unroll
        for (int q = 0; q < 7; ++q) s_red[wave][q] = vals[q];
    }
    __syncthreads();
    if (tid < 7) {
        double acc = (double)s_red[0][tid] + (double)s_red[1][tid]
                   + (double)s_red[2][tid] + (double)s_red[3][tid];
        atomicAdd(&ws[(size_t)(blockIdx.x & (NSLOT - 1)) * 8 + tid], acc);
    }
}

__global__ __launch_bounds__(256) void combined_loss_final(
    const double* __restrict__ ws, float* __restrict__ out)
{
    __shared__ double sred[4][7];
    const int tid = threadIdx.x;
    double v[7];
    #pragma unroll
    for (int q = 0; q < 7; ++q) v[q] = ws[(size_t)tid * 8 + q];
    #pragma unroll
    for (int off = 32; off > 0; off >>= 1) {
        #pragma unroll
        for (int q = 0; q < 7; ++q)
            v[q] += __shfl_down(v[q], off, 64);
    }
    const int wave = tid >> 6, lane = tid & 63;
    if (lane == 0) {
        #pragma unroll
        for (int q = 0; q < 7; ++q) sred[wave][q] = v[q];
    }
    __syncthreads();
    if (tid == 0) {
        double s[7];
        #pragma unroll
        for (int q = 0; q < 7; ++q)
            s[q] = sred[0][q] + sred[1][q] + sred[2][q] + sred[3][q];
        const double robot = s[0] / (double)((size_t)B_DIM * T_DIM * 12);
        const double phase = s[1] / (double)((size_t)B_DIM * T_DIM);
        const double coher = (s[3] > 0.0) ? (s[2] / fmax(s[3], 1.0)) : 0.0;
        const double speed = 5.0  * (s[4] / (double)((size_t)B_DIM * (T_DIM - 1) * 4));
        const double vel   = 0.05 * (s[5] / (double)((size_t)B_DIM * (T_DIM - 1) * 12));
        const double acc   = 0.01 * (s[6] / (double)((size_t)B_DIM * (T_DIM - 2) * 12));
        out[0] = (float)(robot + phase + 10.0 * coher + speed + vel + acc);
    }
}

extern "C" void kernel_launch(void* const* d_in, const int* in_sizes, int n_in,
                              void* d_out, int out_size, void* d_ws, size_t ws_size,
                              hipStream_t stream)
{
    const float4* pred4      = (const float4*)d_in[0];
    const float*  pred_phase = (const float*)d_in[1];
    const float4* gt4        = (const float4*)d_in[2];
    const int*    gt_phase   = (const int*)d_in[3];
    double* ws  = (double*)d_ws;
    float*  out = (float*)d_out;

    hipMemsetAsync(d_ws, 0, (size_t)NSLOT * 8 * sizeof(double), stream);

    combined_loss_main<<<dim3(GRID_BLOCKS), BLOCK, 0, stream>>>(pred4, pred_phase, gt4, gt_phase, ws);
    combined_loss_final<<<1, 256, 0, stream>>>(ws, out);
}